// Round 5
// baseline (113.730 us; speedup 1.0000x reference)
//
#include <hip/hip_runtime.h>

// PointPillars scatter: canvas[b, c, y, x] = feat[n, c] where coords[n] = (b, _, y, x)
// R5: scatter->gather inversion with FILL-SHAPED write pattern.
//   K1: map[:] = -1                     (B*NY*NX ints in d_ws)
//   K2: map[b*NY*NX + y*NX + x] = n     (collision-free per problem spec)
//   K3: grid-stride over OUTPUT LINEAR index, 16 B per thread per iter.
//       All in-flight waves write a compact moving window (like
//       __amd_rocclr_fillBufferAligned, which hits 6.9 TB/s on this machine),
//       instead of 20K scattered per-plane streams (R2/R4: 4.1 TB/s).
//       Map slice for the active b is 640 KB -> L2-resident across the
//       64-channel sweep; feat (24.6 MB) is L3-resident; gathers are
//       exec-masked (~7.5% lanes active).

#define NXD 400
#define NYD 400
#define CCH 64
#define NXY (NXD * NYD)   // 160000 cells/sample, divisible by 4

typedef float fvec4 __attribute__((ext_vector_type(4)));
typedef int   ivec4 __attribute__((ext_vector_type(4)));

__global__ void pps_init_map(ivec4* __restrict__ map4, int total4) {
    int i = blockIdx.x * blockDim.x + threadIdx.x;
    int stride = gridDim.x * blockDim.x;
    ivec4 neg1 = {-1, -1, -1, -1};
    for (; i < total4; i += stride)
        __builtin_nontemporal_store(neg1, map4 + i);
}

__global__ void pps_build_map(const int* __restrict__ coords, int* __restrict__ map, int n) {
    int i = blockIdx.x * blockDim.x + threadIdx.x;
    if (i >= n) return;
    ivec4 c4 = *(const ivec4*)(coords + i * 4);   // (b, _, y, x)
    map[c4.x * NXY + c4.z * NXD + c4.w] = i;
}

__global__ __launch_bounds__(256) void pps_out_linear(const float* __restrict__ feat,
                                                      const int* __restrict__ map,
                                                      float* __restrict__ out,
                                                      int nchunks) {
    int tid = blockIdx.x * blockDim.x + threadIdx.x;
    int stride = gridDim.x * blockDim.x;
    for (int i = tid; i < nchunks; i += stride) {
        int o4 = i * 4;                 // linear float index, < 2^31
        int bc = o4 / NXY;              // magic-mul; bc = b*64 + c
        int s  = o4 - bc * NXY;         // cell index within the plane, %4 == 0
        int b  = bc >> 6;
        int c  = bc & 63;

        ivec4 m = *(const ivec4*)(map + b * NXY + s);   // 16B coalesced, L2-hot

        fvec4 v;
        v.x = (m.x >= 0) ? feat[(size_t)m.x * CCH + c] : 0.0f;  // exec-masked
        v.y = (m.y >= 0) ? feat[(size_t)m.y * CCH + c] : 0.0f;  // gathers,
        v.z = (m.z >= 0) ? feat[(size_t)m.z * CCH + c] : 0.0f;  // ~7.5% lanes
        v.w = (m.w >= 0) ? feat[(size_t)m.w * CCH + c] : 0.0f;  // active

        *(fvec4*)(out + (size_t)o4) = v;   // sequential 16B/lane, 1KB/wave,
                                           // compact moving window grid-wide
    }
}

extern "C" void kernel_launch(void* const* d_in, const int* in_sizes, int n_in,
                              void* d_out, int out_size, void* d_ws, size_t ws_size,
                              hipStream_t stream) {
    const float* feat  = (const float*)d_in[0];   // [N, 64] fp32
    const int* coords  = (const int*)d_in[1];     // [N, 4] int32 (b, _, y, x)
    float* out         = (float*)d_out;           // [B, 64, NY, NX] fp32

    const int n_pillars = in_sizes[1] / 4;
    const int batch     = out_size / (CCH * NXY);
    const int total_pos = batch * NXY;            // 1.28M cells

    int* map = (int*)d_ws;                        // batch*NXY*4 = 5.12 MB

    // K1: reset map every call (d_ws not re-poisoned between replays)
    pps_init_map<<<1024, 256, 0, stream>>>((ivec4*)map, total_pos / 4);

    // K2: scatter pillar indices into the map
    pps_build_map<<<(n_pillars + 255) / 256, 256, 0, stream>>>(coords, map, n_pillars);

    // K3: fill-shaped gather pass over output-linear index
    {
        int nchunks = out_size / 4;               // 20.48M 16B chunks
        pps_out_linear<<<1024, 256, 0, stream>>>(feat, map, out, nchunks);
    }
}